// Round 1
// baseline (255.402 us; speedup 1.0000x reference)
//
#include <hip/hip_runtime.h>

// Problem constants (L=16, K=2, V=2)
constexpr int S_ = 1 << 16;   // 65536 states
constexpr int R_ = 1 << 12;   // 4096 reduced states
constexpr int D_ = 16;        // candidates per reduced state
constexpr int B_ = 512;       // batch
constexpr int BLOCK = 256;    // 4 waves
constexpr int RPT  = 4;       // r per thread (float4 granularity)
constexpr int RPB  = BLOCK * RPT;   // 1024 r per block
constexpr int CHUNKS = R_ / RPB;    // 4 chunks per batch row

// lut[s] depends only on t(s) = ((s+1)*s >> 7) & 255 (256 distinct rows).
// Scatter into a 256-entry table; equal-t writers store identical values.
__global__ __launch_bounds__(256) void build_tab_kernel(
    const float* __restrict__ lut, float2* __restrict__ tab)
{
    const unsigned s = blockIdx.x * 256u + threadIdx.x;
    const unsigned t = (((s + 1u) * s) >> 7) & 255u;
    tab[t] = make_float2(lut[2 * s], lut[2 * s + 1]);
}

// No LDS staging of cost: the tile had zero reuse (phase 1 reads it once).
// Direct per-thread float4 loads along r are equally coalesced (1 KB/wave/d),
// avoid the vmcnt(0) drain before the barrier, and cut LDS 35.8 KB -> 5 KB
// so occupancy is VGPR-bound. __launch_bounds__(256,6): 6 waves/EU = 24
// waves/CU (6 blocks/CU vs 4 before).
__global__ __launch_bounds__(BLOCK, 6) void trellis_kernel(
    const float*  __restrict__ cost,   // (B, S)
    const float*  __restrict__ orig,   // (B, 2)
    const float2* __restrict__ tab,    // (256,) lut rows by t
    float*        __restrict__ prev_state_out, // (B, R) as float
    float*        __restrict__ new_cost)       // (B, S)
{
    __shared__ float lds_bv[RPB];      // 4 KB
    __shared__ float lds_err[256];     // 1 KB

    const int b      = blockIdx.x / CHUNKS;
    const int rchunk = blockIdx.x % CHUNKS;
    const int r0     = rchunk * RPB;
    const int tid    = threadIdx.x;

    const float  o0 = orig[2 * b + 0];
    const float  o1 = orig[2 * b + 1];
    const float2 tv = tab[tid];

    // ---- phase 1: min/argmin over d, 4 r per thread, straight from global ----
    const int r = r0 + tid * RPT;
    const float* pb = cost + (size_t)b * S_ + r;

    float4 bv = *(const float4*)pb;            // d = 0
    int bia = 0, bib = 0, bic = 0, bid_ = 0;
    #pragma unroll
    for (int d = 1; d < D_; ++d) {
        const float4 v = *(const float4*)(pb + (size_t)d * R_);
        if (v.x < bv.x) { bv.x = v.x; bia  = d; }   // strict <: first-min wins
        if (v.y < bv.y) { bv.y = v.y; bib  = d; }
        if (v.z < bv.z) { bv.z = v.z; bic  = d; }
        if (v.w < bv.w) { bv.w = v.w; bid_ = d; }
    }

    // state_candidates[r][d] == r + (d<<12) exactly (closed form; no gather)
    *(float4*)(prev_state_out + (size_t)b * R_ + r) =
        make_float4((float)(r     + (bia  << 12)),
                    (float)(r + 1 + (bib  << 12)),
                    (float)(r + 2 + (bic  << 12)),
                    (float)(r + 3 + (bid_ << 12)));

    *(float4*)(lds_bv + tid * RPT) = bv;

    // per-b squared-error table (256 entries, one per thread)
    {
        const float e0 = tv.x - o0, e1 = tv.y - o1;
        lds_err[tid] = e0 * e0 + e1 * e1;
    }
    __syncthreads();

    // ---- phase 2: new_cost[b,s] = err[t(s)] + bv[s>>4]; contiguous 64 KB ----
    const int s_base = r0 << 4;    // r0 * D_
    float* outb = new_cost + (size_t)b * S_ + s_base;
    #pragma unroll
    for (int it = 0; it < (RPB * D_) / (BLOCK * 4); ++it) {   // 16 iters
        const int flat = it * (BLOCK * 4) + tid * 4;
        const unsigned s = (unsigned)(s_base + flat);
        const float bvv = lds_bv[flat >> 4];   // 4-lane same-addr broadcast
        float4 out;
        out.x = lds_err[(((s + 1u) * (s + 0u)) >> 7) & 255u] + bvv;
        out.y = lds_err[(((s + 2u) * (s + 1u)) >> 7) & 255u] + bvv;
        out.z = lds_err[(((s + 3u) * (s + 2u)) >> 7) & 255u] + bvv;
        out.w = lds_err[(((s + 4u) * (s + 3u)) >> 7) & 255u] + bvv;
        *(float4*)(outb + flat) = out;
    }
}

extern "C" void kernel_launch(void* const* d_in, const int* in_sizes, int n_in,
                              void* d_out, int out_size, void* d_ws, size_t ws_size,
                              hipStream_t stream) {
    const float* lut  = (const float*)d_in[0];   // training_lut (S,2)
    const float* cost = (const float*)d_in[1];   // cost (B,S)
    const float* orig = (const float*)d_in[2];   // orig_seq_part (B,2)
    // d_in[3] = state_candidates — closed form r + (d<<12), not needed on device

    float* prev_state = (float*)d_out;                      // output 0: (B,R)
    float* new_cost   = (float*)d_out + (size_t)B_ * R_;    // output 1: (B,S)
    float2* tab       = (float2*)d_ws;                      // 256 entries (2 KB)

    hipLaunchKernelGGL(build_tab_kernel, dim3(S_ / 256), dim3(256), 0, stream,
                       lut, tab);
    hipLaunchKernelGGL(trellis_kernel, dim3(B_ * CHUNKS), dim3(BLOCK), 0, stream,
                       cost, orig, tab, prev_state, new_cost);
}

// Round 2
// 254.660 us; speedup vs baseline: 1.0029x; 1.0029x over previous
//
#include <hip/hip_runtime.h>

// Problem constants (L=16, K=2, V=2)
constexpr int S_ = 1 << 16;   // 65536 states
constexpr int R_ = 1 << 12;   // 4096 reduced states
constexpr int D_ = 16;        // candidates per reduced state
constexpr int B_ = 512;       // batch
constexpr int BLOCK = 256;    // 4 waves
constexpr int RPT  = 4;       // r per thread (float4 granularity)
constexpr int RPB  = BLOCK * RPT;   // 1024 r per block
constexpr int CHUNKS = R_ / RPB;    // 4 chunks per batch row

// lut[s] depends only on t(s) = ((s+1)*s >> 7) & 255 (256 distinct rows).
// Scatter into a 256-entry table; equal-t writers store identical values.
__global__ __launch_bounds__(256) void build_tab_kernel(
    const float* __restrict__ lut, float2* __restrict__ tab)
{
    const unsigned s = blockIdx.x * 256u + threadIdx.x;
    const unsigned t = (((s + 1u) * s) >> 7) & 255u;
    tab[t] = make_float2(lut[2 * s], lut[2 * s + 1]);
}

// R1 lesson (VGPR_Count=32, 2.5 TB/s, latency-bound): the fused
// load-compare loop let the compiler serialize the 16 d-strided loads.
// Fix: load ALL 16 float4 into registers first (64 VGPRs of payload,
// full per-thread MLP), then reduce. __launch_bounds__(256,4) gives the
// 128-VGPR budget; 4 blocks/CU, 16 waves/CU.
__global__ __launch_bounds__(BLOCK, 4) void trellis_kernel(
    const float*  __restrict__ cost,   // (B, S)
    const float*  __restrict__ orig,   // (B, 2)
    const float2* __restrict__ tab,    // (256,) lut rows by t
    float*        __restrict__ prev_state_out, // (B, R) as float
    float*        __restrict__ new_cost)       // (B, S)
{
    __shared__ float lds_bv[RPB];      // 4 KB
    __shared__ float lds_err[256];     // 1 KB

    const int b      = blockIdx.x / CHUNKS;
    const int rchunk = blockIdx.x % CHUNKS;
    const int r0     = rchunk * RPB;
    const int tid    = threadIdx.x;

    const float  o0 = orig[2 * b + 0];
    const float  o1 = orig[2 * b + 1];
    const float2 tv = tab[tid];

    // ---- phase 1: issue all 16 strided float4 loads up front (full MLP) ----
    const int r = r0 + tid * RPT;
    const float* pb = cost + (size_t)b * S_ + r;

    float4 v[D_];
    #pragma unroll
    for (int d = 0; d < D_; ++d)
        v[d] = *(const float4*)(pb + (size_t)d * R_);

    // per-b squared-error table: pure VALU, overlaps the load latency
    {
        const float e0 = tv.x - o0, e1 = tv.y - o1;
        lds_err[tid] = e0 * e0 + e1 * e1;
    }

    // ---- min/argmin over d in registers; strict <: first-min wins ----
    float4 bv = v[0];
    int bia = 0, bib = 0, bic = 0, bid_ = 0;
    #pragma unroll
    for (int d = 1; d < D_; ++d) {
        if (v[d].x < bv.x) { bv.x = v[d].x; bia  = d; }
        if (v[d].y < bv.y) { bv.y = v[d].y; bib  = d; }
        if (v[d].z < bv.z) { bv.z = v[d].z; bic  = d; }
        if (v[d].w < bv.w) { bv.w = v[d].w; bid_ = d; }
    }

    // state_candidates[r][d] == r + (d<<12) exactly (closed form; no gather)
    *(float4*)(prev_state_out + (size_t)b * R_ + r) =
        make_float4((float)(r     + (bia  << 12)),
                    (float)(r + 1 + (bib  << 12)),
                    (float)(r + 2 + (bic  << 12)),
                    (float)(r + 3 + (bid_ << 12)));

    *(float4*)(lds_bv + tid * RPT) = bv;
    __syncthreads();

    // ---- phase 2: new_cost[b,s] = err[t(s)] + bv[s>>4]; contiguous 64 KB ----
    const int s_base = r0 << 4;    // r0 * D_
    float* outb = new_cost + (size_t)b * S_ + s_base;
    #pragma unroll
    for (int it = 0; it < (RPB * D_) / (BLOCK * 4); ++it) {   // 16 iters
        const int flat = it * (BLOCK * 4) + tid * 4;
        const unsigned s = (unsigned)(s_base + flat);
        const float bvv = lds_bv[flat >> 4];   // 4-lane same-addr broadcast
        float4 out;
        out.x = lds_err[(((s + 1u) * (s + 0u)) >> 7) & 255u] + bvv;
        out.y = lds_err[(((s + 2u) * (s + 1u)) >> 7) & 255u] + bvv;
        out.z = lds_err[(((s + 3u) * (s + 2u)) >> 7) & 255u] + bvv;
        out.w = lds_err[(((s + 4u) * (s + 3u)) >> 7) & 255u] + bvv;
        *(float4*)(outb + flat) = out;
    }
}

extern "C" void kernel_launch(void* const* d_in, const int* in_sizes, int n_in,
                              void* d_out, int out_size, void* d_ws, size_t ws_size,
                              hipStream_t stream) {
    const float* lut  = (const float*)d_in[0];   // training_lut (S,2)
    const float* cost = (const float*)d_in[1];   // cost (B,S)
    const float* orig = (const float*)d_in[2];   // orig_seq_part (B,2)
    // d_in[3] = state_candidates — closed form r + (d<<12), not needed on device

    float* prev_state = (float*)d_out;                      // output 0: (B,R)
    float* new_cost   = (float*)d_out + (size_t)B_ * R_;    // output 1: (B,S)
    float2* tab       = (float2*)d_ws;                      // 256 entries (2 KB)

    hipLaunchKernelGGL(build_tab_kernel, dim3(S_ / 256), dim3(256), 0, stream,
                       lut, tab);
    hipLaunchKernelGGL(trellis_kernel, dim3(B_ * CHUNKS), dim3(BLOCK), 0, stream,
                       cost, orig, tab, prev_state, new_cost);
}